// Round 12
// baseline (629.708 us; speedup 1.0000x reference)
//
#include <hip/hip_runtime.h>
#include <cmath>

#define NUM_LEVELS 16
#define GRID_CH 66
#define BLOCK 256
#define NGRP 8
#define NSL 14            // sliced levels 2..15

typedef float float4n __attribute__((ext_vector_type(4)));
typedef float float2n __attribute__((ext_vector_type(2)));

struct LevelP { int offset; int res_eff; int use_hash; int hsize; float scale; };
struct SlP {
    int   offset[NSL];
    int   res_eff[NSL];
    int   use_hash[NSL];
    int   ssz[NSL];        // slice size in rows = hsize/8
    float scale[NSL];
};

static LevelP g_levels[NUM_LEVELS];
static bool init_levels() {
    long long off = 0;
    const double S = std::log2(2048.0 / 16.0) / 15.0;   // 7/15
    for (int l = 0; l < NUM_LEVELS; ++l) {
        double scale = std::exp2((double)l * S) * 16.0 - 1.0;
        int resolution = (int)std::ceil(scale) + 1;
        int res_eff = resolution + 1;                    // ALIGN_CORNERS = False
        long long cube = (long long)res_eff * res_eff * res_eff;
        long long n = cube < 131072 ? cube : 131072;
        n = ((n + 7) / 8) * 8;
        g_levels[l].offset   = (int)off;
        g_levels[l].res_eff  = res_eff;
        g_levels[l].use_hash = (cube > n) ? 1 : 0;
        g_levels[l].hsize    = (int)n;
        g_levels[l].scale    = (float)scale;
        off += n;
    }
    return true;
}
static bool g_inited = init_levels();

// 8-byte pair, 4-byte alignment (channel index may be odd).
struct __attribute__((packed, aligned(4))) F2 { float x, y; };

// rec[i] = {x,y,z,wa0, wb0,wa1,wb1, bits(ia0|ia1<<8)} : one 32B record/sample.
__global__ __launch_bounds__(BLOCK) void tge_prep(
    const float* __restrict__ inputs, const float* __restrict__ tri,
    float* __restrict__ rec)
{
    const int i = blockIdx.x * BLOCK + threadIdx.x;
    const float4 t0 = *reinterpret_cast<const float4*>(tri + (size_t)i * 8);
    const float4 t1 = *reinterpret_cast<const float4*>(tri + (size_t)i * 8 + 4);
    const unsigned bits = (unsigned)(int)t0.y | ((unsigned)(int)t1.y << 8);
    float4n r0, r1;
    r0.x = inputs[i * 3 + 0]; r0.y = inputs[i * 3 + 1]; r0.z = inputs[i * 3 + 2];
    r0.w = t0.x;                                   // wa0
    r1.x = t0.z; r1.y = t1.x; r1.z = t1.z;         // wb0, wa1, wb1
    r1.w = __uint_as_float(bits);                  // raw bits
    *reinterpret_cast<float4n*>(rec + (size_t)i * 8)     = r0;
    *reinterpret_cast<float4n*>(rec + (size_t)i * 8 + 4) = r1;
}

// Full-table path for levels 0,1 (tables 1.3/3.6 MB: L2-resident everywhere).
__global__ __launch_bounds__(BLOCK) void tge_simple(
    const float* __restrict__ rec, const float* __restrict__ tbl,
    float* __restrict__ acc01, float scale, int R, int use_hash, int B, int l)
{
    const int i = blockIdx.x * BLOCK + threadIdx.x;
    const float4n r0 = *reinterpret_cast<const float4n*>(rec + (size_t)i * 8);
    const float4n r1 = *reinterpret_cast<const float4n*>(rec + (size_t)i * 8 + 4);
    const unsigned iap = __float_as_uint(r1.w);
    const int  ia0 = (int)(iap & 0xffu), ia1 = (int)((iap >> 8) & 0xffu);
    const unsigned base0 = (unsigned)(ia0 < 64 ? ia0 : 64);
    const unsigned base1 = (unsigned)(ia1 < 64 ? ia1 : 64);
    const bool hi0 = (ia0 == 65), hi1 = (ia1 == 65);

    const float px = r0.x * scale + 0.5f;
    const float py = r0.y * scale + 0.5f;
    const float pz = r0.z * scale + 0.5f;
    const float fx = floorf(px), fy = floorf(py), fz = floorf(pz);
    const float rx = px - fx, ry = py - fy, rz = pz - fz;
    const unsigned ux = (unsigned)fx, uy = (unsigned)fy, uz = (unsigned)fz;

    unsigned hx0, hx1, hy0, hy1, hz0, hz1;
    if (use_hash) {
        hx0 = ux;                   hx1 = ux + 1u;
        hy0 = uy * 2654435761u;     hy1 = hy0 + 2654435761u;
        hz0 = uz * 805459861u;      hz1 = hz0 + 805459861u;
    } else {
        hx0 = ux;                   hx1 = ux + 1u;
        hy0 = uy * (unsigned)R;     hy1 = hy0 + (unsigned)R;
        hz0 = uz * (unsigned)(R*R); hz1 = hz0 + (unsigned)(R*R);
    }

    const float w0x = 1.f - rx, w1x = rx;
    const float w0y = 1.f - ry, w1y = ry;
    const float w0z = 1.f - rz, w1z = rz;

    float acc0 = 0.f, acc1 = 0.f;
    #pragma unroll
    for (int c = 0; c < 8; ++c) {
        const unsigned a = (c & 1) ? hx1 : hx0;
        const unsigned b = (c & 2) ? hy1 : hy0;
        const unsigned d = (c & 4) ? hz1 : hz0;
        const unsigned idx = use_hash ? ((a ^ b ^ d) & 131071u) : (a + b + d);
        const float* rowp = tbl + (size_t)idx * GRID_CH;
        const F2 pa0 = *reinterpret_cast<const F2*>(rowp + base0);
        const F2 pa1 = *reinterpret_cast<const F2*>(rowp + base1);
        const float va0 = hi0 ? pa0.y : pa0.x;
        const float va1 = hi1 ? pa1.y : pa1.x;
        float vb0 = pa0.y, vb1 = pa1.y;
        if (hi0) vb0 = rowp[0];
        if (hi1) vb1 = rowp[0];
        const float wx = (c & 1) ? w1x : w0x;
        const float wy = (c & 2) ? w1y : w0y;
        const float wz = (c & 4) ? w1z : w0z;
        const float w = wx * wy * wz;
        acc0 += w * (r0.w * va0 + r1.x * vb0);
        acc1 += w * (r1.y * va1 + r1.z * vb1);
    }
    float2n rr; rr.x = acc0; rr.y = acc1;
    *reinterpret_cast<float2n*>(acc01 + ((size_t)l * B + i) * 2) = rr;
}

// Sliced gather, CHUNK=1 (R9's best gather geometry) + race-free partials.
// z = sliced-level (level z+2), time-phased by x-major dispatch order.
// g = blockIdx.x & 7 -> XCD via round-robin (gridDim.x % 8 == 0). Group g
// gathers only rows [g*ssz, (g+1)*ssz) (~4.3 MB ~ L2-sized) -> slice reuse
// becomes L2 hits on the owning XCD. rec loads are NON-TEMPORAL so the 8 MB
// rec stream doesn't evict the table slice from L2 (it is L3-resident).
// Partials go to the full part[14][8][B] buffer; all reductions happen in
// tge_finish after this kernel completes (stream-order barrier, no races).
__global__ __launch_bounds__(BLOCK) void tge_gather(
    const float* __restrict__ rec, const float* __restrict__ emb,
    float* __restrict__ part,           // [NSL][NGRP][B] float2
    SlP P, int B)
{
    const int z  = blockIdx.z;
    const int g  = blockIdx.x & (NGRP - 1);
    const int i  = (blockIdx.x >> 3) * BLOCK + threadIdx.x;

    const float scale    = P.scale[z];
    const int   R        = P.res_eff[z];
    const int   use_hash = P.use_hash[z];
    const float* __restrict__ tbl = emb + (size_t)P.offset[z] * GRID_CH;
    const unsigned lo = (unsigned)(g * P.ssz[z]);
    const unsigned hc = lo + (unsigned)P.ssz[z];

    const float4n r0 = __builtin_nontemporal_load(
        reinterpret_cast<const float4n*>(rec + (size_t)i * 8));
    const float4n r1 = __builtin_nontemporal_load(
        reinterpret_cast<const float4n*>(rec + (size_t)i * 8 + 4));
    const unsigned iap = __float_as_uint(r1.w);
    const int  ia0 = (int)(iap & 0xffu), ia1 = (int)((iap >> 8) & 0xffu);
    const unsigned base0 = (unsigned)(ia0 < 64 ? ia0 : 64);
    const unsigned base1 = (unsigned)(ia1 < 64 ? ia1 : 64);
    const bool hi0 = (ia0 == 65), hi1 = (ia1 == 65);
    const float wa0 = r0.w, wb0 = r1.x, wa1 = r1.y, wb1 = r1.z;

    const float px = r0.x * scale + 0.5f;
    const float py = r0.y * scale + 0.5f;
    const float pz = r0.z * scale + 0.5f;
    const float fx = floorf(px), fy = floorf(py), fz = floorf(pz);
    const float rx = px - fx, ry = py - fy, rz = pz - fz;
    const unsigned ux = (unsigned)fx, uy = (unsigned)fy, uz = (unsigned)fz;

    unsigned hx0, hx1, hy0, hy1, hz0, hz1;
    if (use_hash) {
        hx0 = ux;                   hx1 = ux + 1u;
        hy0 = uy * 2654435761u;     hy1 = hy0 + 2654435761u;
        hz0 = uz * 805459861u;      hz1 = hz0 + 805459861u;
    } else {
        hx0 = ux;                   hx1 = ux + 1u;
        hy0 = uy * (unsigned)R;     hy1 = hy0 + (unsigned)R;
        hz0 = uz * (unsigned)(R*R); hz1 = hz0 + (unsigned)(R*R);
    }

    // 8 corner rows
    unsigned w_0, w_1, w_2, w_3, w_4, w_5, w_6, w_7;
    if (use_hash) {
        const unsigned a0 = hy0 ^ hz0, a1 = hy1 ^ hz0;
        const unsigned a2 = hy0 ^ hz1, a3 = hy1 ^ hz1;
        w_0 = (hx0 ^ a0) & 131071u;  w_1 = (hx1 ^ a0) & 131071u;
        w_2 = (hx0 ^ a1) & 131071u;  w_3 = (hx1 ^ a1) & 131071u;
        w_4 = (hx0 ^ a2) & 131071u;  w_5 = (hx1 ^ a2) & 131071u;
        w_6 = (hx0 ^ a3) & 131071u;  w_7 = (hx1 ^ a3) & 131071u;
    } else {
        const unsigned a0 = hy0 + hz0, a1 = hy1 + hz0;
        const unsigned a2 = hy0 + hz1, a3 = hy1 + hz1;
        w_0 = hx0 + a0;  w_1 = hx1 + a0;
        w_2 = hx0 + a1;  w_3 = hx1 + a1;
        w_4 = hx0 + a2;  w_5 = hx1 + a2;
        w_6 = hx0 + a3;  w_7 = hx1 + a3;
    }

    const bool m0 = (w_0 >= lo) & (w_0 < hc);
    const bool m1 = (w_1 >= lo) & (w_1 < hc);
    const bool m2 = (w_2 >= lo) & (w_2 < hc);
    const bool m3 = (w_3 >= lo) & (w_3 < hc);
    const bool m4 = (w_4 >= lo) & (w_4 < hc);
    const bool m5 = (w_5 >= lo) & (w_5 < hc);
    const bool m6 = (w_6 >= lo) & (w_6 < hc);
    const bool m7 = (w_7 >= lo) & (w_7 < hc);

    const unsigned t0 = w_0 * (unsigned)GRID_CH;
    const unsigned t1 = w_1 * (unsigned)GRID_CH;
    const unsigned t2 = w_2 * (unsigned)GRID_CH;
    const unsigned t3 = w_3 * (unsigned)GRID_CH;
    const unsigned t4 = w_4 * (unsigned)GRID_CH;
    const unsigned t5 = w_5 * (unsigned)GRID_CH;
    const unsigned t6 = w_6 * (unsigned)GRID_CH;
    const unsigned t7 = w_7 * (unsigned)GRID_CH;

    // Zero-init named pairs; exec-masked clustered loads.
    F2 A0{0,0}, A1{0,0}, A2{0,0}, A3{0,0}, A4{0,0}, A5{0,0}, A6{0,0}, A7{0,0};
    F2 B0{0,0}, B1{0,0}, B2{0,0}, B3{0,0}, B4{0,0}, B5{0,0}, B6{0,0}, B7{0,0};
#define LD2(off) (*reinterpret_cast<const F2*>(tbl + (off)))
    if (m0) { A0 = LD2(t0 + base0); B0 = LD2(t0 + base1); }
    if (m1) { A1 = LD2(t1 + base0); B1 = LD2(t1 + base1); }
    if (m2) { A2 = LD2(t2 + base0); B2 = LD2(t2 + base1); }
    if (m3) { A3 = LD2(t3 + base0); B3 = LD2(t3 + base1); }
    if (m4) { A4 = LD2(t4 + base0); B4 = LD2(t4 + base1); }
    if (m5) { A5 = LD2(t5 + base0); B5 = LD2(t5 + base1); }
    if (m6) { A6 = LD2(t6 + base0); B6 = LD2(t6 + base1); }
    if (m7) { A7 = LD2(t7 + base0); B7 = LD2(t7 + base1); }
#undef LD2

    // vb channels (wrap ia==65 -> channel 0), still slice-masked.
    float q00 = A0.y, q01 = A1.y, q02 = A2.y, q03 = A3.y;
    float q04 = A4.y, q05 = A5.y, q06 = A6.y, q07 = A7.y;
    float q10 = B0.y, q11 = B1.y, q12 = B2.y, q13 = B3.y;
    float q14 = B4.y, q15 = B5.y, q16 = B6.y, q17 = B7.y;
    if (hi0) {
        if (m0) q00 = tbl[t0]; if (m1) q01 = tbl[t1];
        if (m2) q02 = tbl[t2]; if (m3) q03 = tbl[t3];
        if (m4) q04 = tbl[t4]; if (m5) q05 = tbl[t5];
        if (m6) q06 = tbl[t6]; if (m7) q07 = tbl[t7];
    }
    if (hi1) {
        if (m0) q10 = tbl[t0]; if (m1) q11 = tbl[t1];
        if (m2) q12 = tbl[t2]; if (m3) q13 = tbl[t3];
        if (m4) q14 = tbl[t4]; if (m5) q15 = tbl[t5];
        if (m6) q16 = tbl[t6]; if (m7) q17 = tbl[t7];
    }

    const float w0x = 1.f - rx, w1x = rx;
    const float w0y = 1.f - ry, w1y = ry;
    const float w0z = 1.f - rz, w1z = rz;

    float acc0 = 0.f, acc1 = 0.f;
#define CACC(A, Bv, q0v, q1v, w)                         \
    { const float va0 = hi0 ? (A).y : (A).x;             \
      const float va1 = hi1 ? (Bv).y : (Bv).x;           \
      acc0 += (w) * (wa0 * va0 + wb0 * (q0v));           \
      acc1 += (w) * (wa1 * va1 + wb1 * (q1v)); }
    CACC(A0, B0, q00, q10, w0x * w0y * w0z)
    CACC(A1, B1, q01, q11, w1x * w0y * w0z)
    CACC(A2, B2, q02, q12, w0x * w1y * w0z)
    CACC(A3, B3, q03, q13, w1x * w1y * w0z)
    CACC(A4, B4, q04, q14, w0x * w0y * w1z)
    CACC(A5, B5, q05, q15, w1x * w0y * w1z)
    CACC(A6, B6, q06, q16, w0x * w1y * w1z)
    CACC(A7, B7, q07, q17, w1x * w1y * w1z)
#undef CACC

    float2n rr; rr.x = acc0; rr.y = acc1;
    __builtin_nontemporal_store(rr, reinterpret_cast<float2n*>(
        part + (((size_t)z * NGRP + g) * B + i) * 2));
}

// All reductions + transpose: acc01[2][B], part[14][8][B] -> out[B][32].
// Runs after tge_gather completes (stream order) -> no races by construction.
__global__ __launch_bounds__(256) void tge_finish(
    const float* __restrict__ acc01,    // [2][B] float2
    const float* __restrict__ part,     // [NSL][NGRP][B] float2
    float* __restrict__ out, int B)
{
    __shared__ float tile[64][33];
    const int t  = threadIdx.x;
    const int s  = t & 63;
    const int q  = t >> 6;                       // 0..3 -> levels q*4..q*4+3
    const int gs = blockIdx.x * 64 + s;

    #pragma unroll
    for (int j = 0; j < 4; ++j) {
        const int l = q * 4 + j;
        float a0, a1;
        if (l < 2) {
            const float2n v = *reinterpret_cast<const float2n*>(
                acc01 + ((size_t)l * B + gs) * 2);
            a0 = v.x; a1 = v.y;
        } else {
            a0 = 0.f; a1 = 0.f;
            const float* p = part + ((size_t)(l - 2) * NGRP * B + gs) * 2;
            #pragma unroll
            for (int g = 0; g < NGRP; ++g) {
                const float2n v = __builtin_nontemporal_load(
                    reinterpret_cast<const float2n*>(p + (size_t)g * B * 2));
                a0 += v.x; a1 += v.y;
            }
        }
        tile[s][2 * l]     = a0;
        tile[s][2 * l + 1] = a1;
    }
    __syncthreads();

    #pragma unroll
    for (int k2 = 0; k2 < 2; ++k2) {
        const int gf = t + k2 * 256;
        const int ss = gf >> 3;
        const int c  = (gf & 7) * 4;
        const float4 v = make_float4(tile[ss][c], tile[ss][c + 1],
                                     tile[ss][c + 2], tile[ss][c + 3]);
        *reinterpret_cast<float4*>(out + ((size_t)(blockIdx.x * 64 + ss)) * 32 + c) = v;
    }
}

// Fallback (ws too small): direct per-level path into out (R8 structure).
__global__ __launch_bounds__(BLOCK) void tge_level(
    const float* __restrict__ inputs, const float* __restrict__ tri,
    const float* __restrict__ tbl, float* __restrict__ dst,
    float scale, int R, int use_hash)
{
    const int i = blockIdx.x * BLOCK + threadIdx.x;
    const float x = inputs[i * 3 + 0];
    const float y = inputs[i * 3 + 1];
    const float z = inputs[i * 3 + 2];
    const float4 t0 = *reinterpret_cast<const float4*>(tri + (size_t)i * 8);
    const float4 t1 = *reinterpret_cast<const float4*>(tri + (size_t)i * 8 + 4);
    const int  ia0 = (int)t0.y, ia1 = (int)t1.y;
    const int  base0 = ia0 < 64 ? ia0 : 64;
    const int  base1 = ia1 < 64 ? ia1 : 64;
    const bool hi0 = (ia0 == 65), hi1 = (ia1 == 65);

    const float px = x * scale + 0.5f;
    const float py = y * scale + 0.5f;
    const float pz = z * scale + 0.5f;
    const float fx = floorf(px), fy = floorf(py), fz = floorf(pz);
    const float rx = px - fx, ry = py - fy, rz = pz - fz;
    const unsigned ux = (unsigned)fx, uy = (unsigned)fy, uz = (unsigned)fz;

    unsigned hx0, hx1, hy0, hy1, hz0, hz1;
    if (use_hash) {
        hx0 = ux;                   hx1 = ux + 1u;
        hy0 = uy * 2654435761u;     hy1 = hy0 + 2654435761u;
        hz0 = uz * 805459861u;      hz1 = hz0 + 805459861u;
    } else {
        hx0 = ux;                   hx1 = ux + 1u;
        hy0 = uy * (unsigned)R;     hy1 = hy0 + (unsigned)R;
        hz0 = uz * (unsigned)(R*R); hz1 = hz0 + (unsigned)(R*R);
    }

    const float w0x = 1.f - rx, w1x = rx;
    const float w0y = 1.f - ry, w1y = ry;
    const float w0z = 1.f - rz, w1z = rz;

    float acc0 = 0.f, acc1 = 0.f;
    #pragma unroll
    for (int c = 0; c < 8; ++c) {
        const unsigned a = (c & 1) ? hx1 : hx0;
        const unsigned b = (c & 2) ? hy1 : hy0;
        const unsigned d = (c & 4) ? hz1 : hz0;
        const unsigned idx = use_hash ? ((a ^ b ^ d) & 131071u) : (a + b + d);
        const float* rowp = tbl + (size_t)idx * GRID_CH;
        const F2 pa0 = *reinterpret_cast<const F2*>(rowp + base0);
        const F2 pa1 = *reinterpret_cast<const F2*>(rowp + base1);
        const float va0 = hi0 ? pa0.y : pa0.x;
        const float va1 = hi1 ? pa1.y : pa1.x;
        float vb0 = pa0.y, vb1 = pa1.y;
        if (hi0) vb0 = rowp[0];
        if (hi1) vb1 = rowp[0];
        const float wx = (c & 1) ? w1x : w0x;
        const float wy = (c & 2) ? w1y : w0y;
        const float wz = (c & 4) ? w1z : w0z;
        const float w = wx * wy * wz;
        acc0 += w * (t0.x * va0 + t0.z * vb0);
        acc1 += w * (t1.x * va1 + t1.z * vb1);
    }
    *reinterpret_cast<float2*>(dst + (size_t)i * 32) = make_float2(acc0, acc1);
}

extern "C" void kernel_launch(void* const* d_in, const int* in_sizes, int n_in,
                              void* d_out, int out_size, void* d_ws, size_t ws_size,
                              hipStream_t stream) {
    const float* inputs = (const float*)d_in[0];
    const float* tri    = (const float*)d_in[1];
    const float* emb    = (const float*)d_in[2];
    float* out          = (float*)d_out;

    const int B = in_sizes[0] / 3;           // 262144

    // ws layout: rec[B*8] | acc01[2][B] float2 | part[14][8][B] float2 (235MB)
    float* rec   = (float*)d_ws;
    float* acc01 = rec + (size_t)B * 8;
    float* part  = acc01 + (size_t)2 * B * 2;
    const size_t need = ((size_t)B * 8 + (size_t)2 * B * 2 +
                         (size_t)NSL * NGRP * B * 2) * sizeof(float);

    if (ws_size < need) {                    // fallback: direct path
        for (int l = 0; l < NUM_LEVELS; ++l) {
            const LevelP& P = g_levels[l];
            tge_level<<<dim3(B / BLOCK), BLOCK, 0, stream>>>(
                inputs, tri, emb + (size_t)P.offset * GRID_CH,
                out + 2 * l, P.scale, P.res_eff, P.use_hash);
        }
        return;
    }

    SlP SP;
    for (int li = 0; li < NSL; ++li) {
        const LevelP& P = g_levels[li + 2];
        SP.offset[li]   = P.offset;
        SP.res_eff[li]  = P.res_eff;
        SP.use_hash[li] = P.use_hash;
        SP.ssz[li]      = P.hsize / NGRP;    // hsize % 8 == 0 by construction
        SP.scale[li]    = P.scale;
    }

    tge_prep<<<dim3(B / BLOCK), BLOCK, 0, stream>>>(inputs, tri, rec);

    for (int l = 0; l < 2; ++l) {
        const LevelP& P = g_levels[l];
        tge_simple<<<dim3(B / BLOCK), BLOCK, 0, stream>>>(
            rec, emb + (size_t)P.offset * GRID_CH, acc01,
            P.scale, P.res_eff, P.use_hash, B, l);
    }

    const int ngx = NGRP * (B / BLOCK);      // 8192 (mult of 8)
    tge_gather<<<dim3(ngx, 1, NSL), BLOCK, 0, stream>>>(rec, emb, part, SP, B);

    tge_finish<<<dim3(B / 64), 256, 0, stream>>>(acc01, part, out, B);
}

// Round 14
// 511.619 us; speedup vs baseline: 1.2308x; 1.2308x over previous
//
#include <hip/hip_runtime.h>
#include <cmath>

#define NUM_LEVELS 16
#define GRID_CH 66
#define BLOCK 256
#define NGRP 8
#define NSL 14            // sliced levels 2..15

typedef float float4n __attribute__((ext_vector_type(4)));
typedef float float2n __attribute__((ext_vector_type(2)));

struct LevelP { int offset; int res_eff; int use_hash; int hsize; float scale; };
struct SlP {
    int   offset[NSL];
    int   res_eff[NSL];
    int   use_hash[NSL];
    int   ssz[NSL];        // slice size in rows = hsize/8
    float scale[NSL];
};

static LevelP g_levels[NUM_LEVELS];
static bool init_levels() {
    long long off = 0;
    const double S = std::log2(2048.0 / 16.0) / 15.0;   // 7/15
    for (int l = 0; l < NUM_LEVELS; ++l) {
        double scale = std::exp2((double)l * S) * 16.0 - 1.0;
        int resolution = (int)std::ceil(scale) + 1;
        int res_eff = resolution + 1;                    // ALIGN_CORNERS = False
        long long cube = (long long)res_eff * res_eff * res_eff;
        long long n = cube < 131072 ? cube : 131072;
        n = ((n + 7) / 8) * 8;
        g_levels[l].offset   = (int)off;
        g_levels[l].res_eff  = res_eff;
        g_levels[l].use_hash = (cube > n) ? 1 : 0;
        g_levels[l].hsize    = (int)n;
        g_levels[l].scale    = (float)scale;
        off += n;
    }
    return true;
}
static bool g_inited = init_levels();

// 8-byte pair, 4-byte alignment (channel index may be odd).
struct __attribute__((packed, aligned(4))) F2 { float x, y; };

// rec[i] = {x,y,z,wa0, wb0,wa1,wb1, bits(ia0|ia1<<8)} : one 32B record/sample.
__global__ __launch_bounds__(BLOCK) void tge_prep(
    const float* __restrict__ inputs, const float* __restrict__ tri,
    float* __restrict__ rec)
{
    const int i = blockIdx.x * BLOCK + threadIdx.x;
    const float4 t0 = *reinterpret_cast<const float4*>(tri + (size_t)i * 8);
    const float4 t1 = *reinterpret_cast<const float4*>(tri + (size_t)i * 8 + 4);
    const unsigned bits = (unsigned)(int)t0.y | ((unsigned)(int)t1.y << 8);
    float4n r0, r1;
    r0.x = inputs[i * 3 + 0]; r0.y = inputs[i * 3 + 1]; r0.z = inputs[i * 3 + 2];
    r0.w = t0.x;                                   // wa0
    r1.x = t0.z; r1.y = t1.x; r1.z = t1.z;         // wb0, wa1, wb1
    r1.w = __uint_as_float(bits);                  // raw bits
    *reinterpret_cast<float4n*>(rec + (size_t)i * 8)     = r0;
    *reinterpret_cast<float4n*>(rec + (size_t)i * 8 + 4) = r1;
}

// Full-table path for levels 0,1 (tables 1.3/3.2 MB: L2-resident everywhere).
__global__ __launch_bounds__(BLOCK) void tge_simple(
    const float* __restrict__ rec, const float* __restrict__ tbl,
    float* __restrict__ acc01, float scale, int R, int use_hash, int B, int l)
{
    const int i = blockIdx.x * BLOCK + threadIdx.x;
    const float4n r0 = *reinterpret_cast<const float4n*>(rec + (size_t)i * 8);
    const float4n r1 = *reinterpret_cast<const float4n*>(rec + (size_t)i * 8 + 4);
    const unsigned iap = __float_as_uint(r1.w);
    const int  ia0 = (int)(iap & 0xffu), ia1 = (int)((iap >> 8) & 0xffu);
    const unsigned base0 = (unsigned)(ia0 < 64 ? ia0 : 64);
    const unsigned base1 = (unsigned)(ia1 < 64 ? ia1 : 64);
    const bool hi0 = (ia0 == 65), hi1 = (ia1 == 65);

    const float px = r0.x * scale + 0.5f;
    const float py = r0.y * scale + 0.5f;
    const float pz = r0.z * scale + 0.5f;
    const float fx = floorf(px), fy = floorf(py), fz = floorf(pz);
    const float rx = px - fx, ry = py - fy, rz = pz - fz;
    const unsigned ux = (unsigned)fx, uy = (unsigned)fy, uz = (unsigned)fz;

    unsigned hx0, hx1, hy0, hy1, hz0, hz1;
    if (use_hash) {
        hx0 = ux;                   hx1 = ux + 1u;
        hy0 = uy * 2654435761u;     hy1 = hy0 + 2654435761u;
        hz0 = uz * 805459861u;      hz1 = hz0 + 805459861u;
    } else {
        hx0 = ux;                   hx1 = ux + 1u;
        hy0 = uy * (unsigned)R;     hy1 = hy0 + (unsigned)R;
        hz0 = uz * (unsigned)(R*R); hz1 = hz0 + (unsigned)(R*R);
    }

    const float w0x = 1.f - rx, w1x = rx;
    const float w0y = 1.f - ry, w1y = ry;
    const float w0z = 1.f - rz, w1z = rz;

    float acc0 = 0.f, acc1 = 0.f;
    #pragma unroll
    for (int c = 0; c < 8; ++c) {
        const unsigned a = (c & 1) ? hx1 : hx0;
        const unsigned b = (c & 2) ? hy1 : hy0;
        const unsigned d = (c & 4) ? hz1 : hz0;
        const unsigned idx = use_hash ? ((a ^ b ^ d) & 131071u) : (a + b + d);
        const float* rowp = tbl + (size_t)idx * GRID_CH;
        const F2 pa0 = *reinterpret_cast<const F2*>(rowp + base0);
        const F2 pa1 = *reinterpret_cast<const F2*>(rowp + base1);
        const float va0 = hi0 ? pa0.y : pa0.x;
        const float va1 = hi1 ? pa1.y : pa1.x;
        float vb0 = pa0.y, vb1 = pa1.y;
        if (hi0) vb0 = rowp[0];
        if (hi1) vb1 = rowp[0];
        const float wx = (c & 1) ? w1x : w0x;
        const float wy = (c & 2) ? w1y : w0y;
        const float wz = (c & 4) ? w1z : w0z;
        const float w = wx * wy * wz;
        acc0 += w * (r0.w * va0 + r1.x * vb0);
        acc1 += w * (r1.y * va1 + r1.z * vb1);
    }
    float2n rr; rr.x = acc0; rr.y = acc1;
    *reinterpret_cast<float2n*>(acc01 + ((size_t)l * B + i) * 2) = rr;
}

// Sliced gather, CHUNK=1, race-free full partials. ALL cross-kernel handoffs
// use REGULAR (cached) loads/stores: R9-R13 used nontemporal stores/loads on
// the part buffer and R13 flaked post-timing (one element read before the nt
// store's visibility) -- the plain cached path is the only one with a 100%
// pass record here (R1-R8).
// z = sliced-level (level z+2), time-phased by x-major dispatch order.
// g = blockIdx.x & 7 -> XCD via round-robin (gridDim.x % 8 == 0). Group g
// gathers only rows [g*ssz, (g+1)*ssz) (~4.3 MB ~ L2-sized) -> slice reuse
// becomes L2 hits on the owning XCD.
__global__ __launch_bounds__(BLOCK) void tge_gather(
    const float* __restrict__ rec, const float* __restrict__ emb,
    float* __restrict__ part,           // [NSL][NGRP][B] float2
    SlP P, int B)
{
    const int z  = blockIdx.z;
    const int g  = blockIdx.x & (NGRP - 1);
    const int i  = (blockIdx.x >> 3) * BLOCK + threadIdx.x;

    const float scale    = P.scale[z];
    const int   R        = P.res_eff[z];
    const int   use_hash = P.use_hash[z];
    const float* __restrict__ tbl = emb + (size_t)P.offset[z] * GRID_CH;
    const unsigned lo = (unsigned)(g * P.ssz[z]);
    const unsigned hc = lo + (unsigned)P.ssz[z];

    const float4n r0 = *reinterpret_cast<const float4n*>(rec + (size_t)i * 8);
    const float4n r1 = *reinterpret_cast<const float4n*>(rec + (size_t)i * 8 + 4);
    const unsigned iap = __float_as_uint(r1.w);
    const int  ia0 = (int)(iap & 0xffu), ia1 = (int)((iap >> 8) & 0xffu);
    const unsigned base0 = (unsigned)(ia0 < 64 ? ia0 : 64);
    const unsigned base1 = (unsigned)(ia1 < 64 ? ia1 : 64);
    const bool hi0 = (ia0 == 65), hi1 = (ia1 == 65);
    const float wa0 = r0.w, wb0 = r1.x, wa1 = r1.y, wb1 = r1.z;

    const float px = r0.x * scale + 0.5f;
    const float py = r0.y * scale + 0.5f;
    const float pz = r0.z * scale + 0.5f;
    const float fx = floorf(px), fy = floorf(py), fz = floorf(pz);
    const float rx = px - fx, ry = py - fy, rz = pz - fz;
    const unsigned ux = (unsigned)fx, uy = (unsigned)fy, uz = (unsigned)fz;

    unsigned hx0, hx1, hy0, hy1, hz0, hz1;
    if (use_hash) {
        hx0 = ux;                   hx1 = ux + 1u;
        hy0 = uy * 2654435761u;     hy1 = hy0 + 2654435761u;
        hz0 = uz * 805459861u;      hz1 = hz0 + 805459861u;
    } else {
        hx0 = ux;                   hx1 = ux + 1u;
        hy0 = uy * (unsigned)R;     hy1 = hy0 + (unsigned)R;
        hz0 = uz * (unsigned)(R*R); hz1 = hz0 + (unsigned)(R*R);
    }

    // 8 corner rows
    unsigned w_0, w_1, w_2, w_3, w_4, w_5, w_6, w_7;
    if (use_hash) {
        const unsigned a0 = hy0 ^ hz0, a1 = hy1 ^ hz0;
        const unsigned a2 = hy0 ^ hz1, a3 = hy1 ^ hz1;
        w_0 = (hx0 ^ a0) & 131071u;  w_1 = (hx1 ^ a0) & 131071u;
        w_2 = (hx0 ^ a1) & 131071u;  w_3 = (hx1 ^ a1) & 131071u;
        w_4 = (hx0 ^ a2) & 131071u;  w_5 = (hx1 ^ a2) & 131071u;
        w_6 = (hx0 ^ a3) & 131071u;  w_7 = (hx1 ^ a3) & 131071u;
    } else {
        const unsigned a0 = hy0 + hz0, a1 = hy1 + hz0;
        const unsigned a2 = hy0 + hz1, a3 = hy1 + hz1;
        w_0 = hx0 + a0;  w_1 = hx1 + a0;
        w_2 = hx0 + a1;  w_3 = hx1 + a1;
        w_4 = hx0 + a2;  w_5 = hx1 + a2;
        w_6 = hx0 + a3;  w_7 = hx1 + a3;
    }

    const bool m0 = (w_0 >= lo) & (w_0 < hc);
    const bool m1 = (w_1 >= lo) & (w_1 < hc);
    const bool m2 = (w_2 >= lo) & (w_2 < hc);
    const bool m3 = (w_3 >= lo) & (w_3 < hc);
    const bool m4 = (w_4 >= lo) & (w_4 < hc);
    const bool m5 = (w_5 >= lo) & (w_5 < hc);
    const bool m6 = (w_6 >= lo) & (w_6 < hc);
    const bool m7 = (w_7 >= lo) & (w_7 < hc);

    const unsigned t0 = w_0 * (unsigned)GRID_CH;
    const unsigned t1 = w_1 * (unsigned)GRID_CH;
    const unsigned t2 = w_2 * (unsigned)GRID_CH;
    const unsigned t3 = w_3 * (unsigned)GRID_CH;
    const unsigned t4 = w_4 * (unsigned)GRID_CH;
    const unsigned t5 = w_5 * (unsigned)GRID_CH;
    const unsigned t6 = w_6 * (unsigned)GRID_CH;
    const unsigned t7 = w_7 * (unsigned)GRID_CH;

    // Zero-init named pairs; exec-masked clustered loads.
    F2 A0{0,0}, A1{0,0}, A2{0,0}, A3{0,0}, A4{0,0}, A5{0,0}, A6{0,0}, A7{0,0};
    F2 B0{0,0}, B1{0,0}, B2{0,0}, B3{0,0}, B4{0,0}, B5{0,0}, B6{0,0}, B7{0,0};
#define LD2(off) (*reinterpret_cast<const F2*>(tbl + (off)))
    if (m0) { A0 = LD2(t0 + base0); B0 = LD2(t0 + base1); }
    if (m1) { A1 = LD2(t1 + base0); B1 = LD2(t1 + base1); }
    if (m2) { A2 = LD2(t2 + base0); B2 = LD2(t2 + base1); }
    if (m3) { A3 = LD2(t3 + base0); B3 = LD2(t3 + base1); }
    if (m4) { A4 = LD2(t4 + base0); B4 = LD2(t4 + base1); }
    if (m5) { A5 = LD2(t5 + base0); B5 = LD2(t5 + base1); }
    if (m6) { A6 = LD2(t6 + base0); B6 = LD2(t6 + base1); }
    if (m7) { A7 = LD2(t7 + base0); B7 = LD2(t7 + base1); }
#undef LD2

    // vb channels (wrap ia==65 -> channel 0), still slice-masked.
    float q00 = A0.y, q01 = A1.y, q02 = A2.y, q03 = A3.y;
    float q04 = A4.y, q05 = A5.y, q06 = A6.y, q07 = A7.y;
    float q10 = B0.y, q11 = B1.y, q12 = B2.y, q13 = B3.y;
    float q14 = B4.y, q15 = B5.y, q16 = B6.y, q17 = B7.y;
    if (hi0) {
        if (m0) q00 = tbl[t0]; if (m1) q01 = tbl[t1];
        if (m2) q02 = tbl[t2]; if (m3) q03 = tbl[t3];
        if (m4) q04 = tbl[t4]; if (m5) q05 = tbl[t5];
        if (m6) q06 = tbl[t6]; if (m7) q07 = tbl[t7];
    }
    if (hi1) {
        if (m0) q10 = tbl[t0]; if (m1) q11 = tbl[t1];
        if (m2) q12 = tbl[t2]; if (m3) q13 = tbl[t3];
        if (m4) q14 = tbl[t4]; if (m5) q15 = tbl[t5];
        if (m6) q16 = tbl[t6]; if (m7) q17 = tbl[t7];
    }

    const float w0x = 1.f - rx, w1x = rx;
    const float w0y = 1.f - ry, w1y = ry;
    const float w0z = 1.f - rz, w1z = rz;

    float acc0 = 0.f, acc1 = 0.f;
#define CACC(A, Bv, q0v, q1v, w)                         \
    { const float va0 = hi0 ? (A).y : (A).x;             \
      const float va1 = hi1 ? (Bv).y : (Bv).x;           \
      acc0 += (w) * (wa0 * va0 + wb0 * (q0v));           \
      acc1 += (w) * (wa1 * va1 + wb1 * (q1v)); }
    CACC(A0, B0, q00, q10, w0x * w0y * w0z)
    CACC(A1, B1, q01, q11, w1x * w0y * w0z)
    CACC(A2, B2, q02, q12, w0x * w1y * w0z)
    CACC(A3, B3, q03, q13, w1x * w1y * w0z)
    CACC(A4, B4, q04, q14, w0x * w0y * w1z)
    CACC(A5, B5, q05, q15, w1x * w0y * w1z)
    CACC(A6, B6, q06, q16, w0x * w1y * w1z)
    CACC(A7, B7, q07, q17, w1x * w1y * w1z)
#undef CACC

    float2n rr; rr.x = acc0; rr.y = acc1;
    *reinterpret_cast<float2n*>(
        part + (((size_t)z * NGRP + g) * B + i) * 2) = rr;
}

// All reductions + transpose: acc01[2][B], part[14][8][B] -> out[B][32].
// Runs after tge_gather completes (stream order). Regular cached loads only.
__global__ __launch_bounds__(256) void tge_finish(
    const float* __restrict__ acc01,    // [2][B] float2
    const float* __restrict__ part,     // [NSL][NGRP][B] float2
    float* __restrict__ out, int B)
{
    __shared__ float tile[64][33];
    const int t  = threadIdx.x;
    const int s  = t & 63;
    const int q  = t >> 6;                       // 0..3 -> levels q*4..q*4+3
    const int gs = blockIdx.x * 64 + s;

    #pragma unroll
    for (int j = 0; j < 4; ++j) {
        const int l = q * 4 + j;
        float a0, a1;
        if (l < 2) {
            const float2n v = *reinterpret_cast<const float2n*>(
                acc01 + ((size_t)l * B + gs) * 2);
            a0 = v.x; a1 = v.y;
        } else {
            a0 = 0.f; a1 = 0.f;
            const float* p = part + ((size_t)(l - 2) * NGRP * B + gs) * 2;
            #pragma unroll
            for (int g = 0; g < NGRP; ++g) {
                const float2n v = *reinterpret_cast<const float2n*>(
                    p + (size_t)g * B * 2);
                a0 += v.x; a1 += v.y;
            }
        }
        tile[s][2 * l]     = a0;
        tile[s][2 * l + 1] = a1;
    }
    __syncthreads();

    #pragma unroll
    for (int k2 = 0; k2 < 2; ++k2) {
        const int gf = t + k2 * 256;
        const int ss = gf >> 3;
        const int c  = (gf & 7) * 4;
        const float4 v = make_float4(tile[ss][c], tile[ss][c + 1],
                                     tile[ss][c + 2], tile[ss][c + 3]);
        *reinterpret_cast<float4*>(out + ((size_t)(blockIdx.x * 64 + ss)) * 32 + c) = v;
    }
}

// Fallback (ws too small): direct per-level path into out (R8 structure).
__global__ __launch_bounds__(BLOCK) void tge_level(
    const float* __restrict__ inputs, const float* __restrict__ tri,
    const float* __restrict__ tbl, float* __restrict__ dst,
    float scale, int R, int use_hash)
{
    const int i = blockIdx.x * BLOCK + threadIdx.x;
    const float x = inputs[i * 3 + 0];
    const float y = inputs[i * 3 + 1];
    const float z = inputs[i * 3 + 2];
    const float4 t0 = *reinterpret_cast<const float4*>(tri + (size_t)i * 8);
    const float4 t1 = *reinterpret_cast<const float4*>(tri + (size_t)i * 8 + 4);
    const int  ia0 = (int)t0.y, ia1 = (int)t1.y;
    const int  base0 = ia0 < 64 ? ia0 : 64;
    const int  base1 = ia1 < 64 ? ia1 : 64;
    const bool hi0 = (ia0 == 65), hi1 = (ia1 == 65);

    const float px = x * scale + 0.5f;
    const float py = y * scale + 0.5f;
    const float pz = z * scale + 0.5f;
    const float fx = floorf(px), fy = floorf(py), fz = floorf(pz);
    const float rx = px - fx, ry = py - fy, rz = pz - fz;
    const unsigned ux = (unsigned)fx, uy = (unsigned)fy, uz = (unsigned)fz;

    unsigned hx0, hx1, hy0, hy1, hz0, hz1;
    if (use_hash) {
        hx0 = ux;                   hx1 = ux + 1u;
        hy0 = uy * 2654435761u;     hy1 = hy0 + 2654435761u;
        hz0 = uz * 805459861u;      hz1 = hz0 + 805459861u;
    } else {
        hx0 = ux;                   hx1 = ux + 1u;
        hy0 = uy * (unsigned)R;     hy1 = hy0 + (unsigned)R;
        hz0 = uz * (unsigned)(R*R); hz1 = hz0 + (unsigned)(R*R);
    }

    const float w0x = 1.f - rx, w1x = rx;
    const float w0y = 1.f - ry, w1y = ry;
    const float w0z = 1.f - rz, w1z = rz;

    float acc0 = 0.f, acc1 = 0.f;
    #pragma unroll
    for (int c = 0; c < 8; ++c) {
        const unsigned a = (c & 1) ? hx1 : hx0;
        const unsigned b = (c & 2) ? hy1 : hy0;
        const unsigned d = (c & 4) ? hz1 : hz0;
        const unsigned idx = use_hash ? ((a ^ b ^ d) & 131071u) : (a + b + d);
        const float* rowp = tbl + (size_t)idx * GRID_CH;
        const F2 pa0 = *reinterpret_cast<const F2*>(rowp + base0);
        const F2 pa1 = *reinterpret_cast<const F2*>(rowp + base1);
        const float va0 = hi0 ? pa0.y : pa0.x;
        const float va1 = hi1 ? pa1.y : pa1.x;
        float vb0 = pa0.y, vb1 = pa1.y;
        if (hi0) vb0 = rowp[0];
        if (hi1) vb1 = rowp[0];
        const float wx = (c & 1) ? w1x : w0x;
        const float wy = (c & 2) ? w1y : w0y;
        const float wz = (c & 4) ? w1z : w0z;
        const float w = wx * wy * wz;
        acc0 += w * (t0.x * va0 + t0.z * vb0);
        acc1 += w * (t1.x * va1 + t1.z * vb1);
    }
    *reinterpret_cast<float2*>(dst + (size_t)i * 32) = make_float2(acc0, acc1);
}

extern "C" void kernel_launch(void* const* d_in, const int* in_sizes, int n_in,
                              void* d_out, int out_size, void* d_ws, size_t ws_size,
                              hipStream_t stream) {
    const float* inputs = (const float*)d_in[0];
    const float* tri    = (const float*)d_in[1];
    const float* emb    = (const float*)d_in[2];
    float* out          = (float*)d_out;

    const int B = in_sizes[0] / 3;           // 262144

    // ws layout: rec[B*8] | acc01[2][B] float2 | part[14][8][B] float2 (235MB)
    float* rec   = (float*)d_ws;
    float* acc01 = rec + (size_t)B * 8;
    float* part  = acc01 + (size_t)2 * B * 2;
    const size_t need = ((size_t)B * 8 + (size_t)2 * B * 2 +
                         (size_t)NSL * NGRP * B * 2) * sizeof(float);

    if (ws_size < need) {                    // fallback: direct path
        for (int l = 0; l < NUM_LEVELS; ++l) {
            const LevelP& P = g_levels[l];
            tge_level<<<dim3(B / BLOCK), BLOCK, 0, stream>>>(
                inputs, tri, emb + (size_t)P.offset * GRID_CH,
                out + 2 * l, P.scale, P.res_eff, P.use_hash);
        }
        return;
    }

    SlP SP;
    for (int li = 0; li < NSL; ++li) {
        const LevelP& P = g_levels[li + 2];
        SP.offset[li]   = P.offset;
        SP.res_eff[li]  = P.res_eff;
        SP.use_hash[li] = P.use_hash;
        SP.ssz[li]      = P.hsize / NGRP;    // hsize % 8 == 0 by construction
        SP.scale[li]    = P.scale;
    }

    tge_prep<<<dim3(B / BLOCK), BLOCK, 0, stream>>>(inputs, tri, rec);

    for (int l = 0; l < 2; ++l) {
        const LevelP& P = g_levels[l];
        tge_simple<<<dim3(B / BLOCK), BLOCK, 0, stream>>>(
            rec, emb + (size_t)P.offset * GRID_CH, acc01,
            P.scale, P.res_eff, P.use_hash, B, l);
    }

    const int ngx = NGRP * (B / BLOCK);      // 8192 (mult of 8)
    tge_gather<<<dim3(ngx, 1, NSL), BLOCK, 0, stream>>>(rec, emb, part, SP, B);

    tge_finish<<<dim3(B / 64), 256, 0, stream>>>(acc01, part, out, B);
}